// Round 3
// baseline (492.397 us; speedup 1.0000x reference)
//
#include <hip/hip_runtime.h>

// SelfAttention: B=8, S=2048, D=1024, U=1024, fp32 in/out.
// R3: 32x32x16 MFMA cores (2x2 frags/wave, 17% fewer MFMA-busy cycles) +
// rowsum folded into pv (computed inline from P A-fragments; scores epilogue
// is exp+store only — no shuffles/atomics/rowsum buffer).
// Staging: global_load_lds(16B) async + XOR-swizzled LDS (slot (row,c8) holds
// global colgroup c8^(row&7)); verified 0 bank conflicts in R2.
// Workspace: 33.6(Xh) + 6.3(WbT) + 33.6*3(QKV) + 67.1(P) = 207.7 MB

#define BM 128
#define BN 128
#define BK 64

typedef _Float16 half8   __attribute__((ext_vector_type(8)));
typedef _Float16 half2v  __attribute__((ext_vector_type(2)));
typedef float    floatx16 __attribute__((ext_vector_type(16)));

// ---- async stage: 128x64 fp16 tile (row-major, ld elems) -> LDS, swizzled ----
__device__ __forceinline__ void stage_async(const _Float16* __restrict__ src, int ld,
                                            _Float16* __restrict__ dst, int wave, int lane) {
#pragma unroll
    for (int i = 0; i < 4; ++i) {
        int chunk = i * 4 + wave;
        int L = chunk * 64 + lane;
        int row = L >> 3, c8 = L & 7;
        int cg = c8 ^ (row & 7);
        __builtin_amdgcn_global_load_lds(
            (const __attribute__((address_space(1))) unsigned int*)(src + (size_t)row * ld + cg * 8),
            (__attribute__((address_space(3))) unsigned int*)(dst + chunk * 512),
            16, 0, 0);
    }
}

// ---- one BK=64 K-step: 16 MFMAs 32x32x16, 2x2 frags/wave ----
// A-frag: row=lane&31, k=(lane>>5)*8+j (8 contiguous halves). B-frag same shape.
__device__ __forceinline__ void mfma_accum(const _Float16* __restrict__ As,
                                           const _Float16* __restrict__ Bs,
                                           int wm, int wn, int l31, int h,
                                           floatx16 acc[2][2]) {
#pragma unroll
    for (int kc = 0; kc < 4; ++kc) {
        int kh = kc * 2 + h;
        half8 a[2], b[2];
#pragma unroll
        for (int fi = 0; fi < 2; ++fi) {
            int row = wm * 64 + fi * 32 + l31;
            a[fi] = *(const half8*)(As + row * 64 + (kh ^ (row & 7)) * 8);
        }
#pragma unroll
        for (int fj = 0; fj < 2; ++fj) {
            int row = wn * 64 + fj * 32 + l31;
            b[fj] = *(const half8*)(Bs + row * 64 + (kh ^ (row & 7)) * 8);
        }
#pragma unroll
        for (int fi = 0; fi < 2; ++fi)
#pragma unroll
            for (int fj = 0; fj < 2; ++fj)
                acc[fi][fj] = __builtin_amdgcn_mfma_f32_32x32x16_f16(a[fi], b[fj], acc[fi][fj], 0, 0, 0);
    }
}

// pk-add sum of 8 halves -> float (3 pk_add + 2 cvt + 1 add)
__device__ __forceinline__ float sum8h(half8 a) {
    union { half8 v; half2v h2[4]; } u; u.v = a;
    half2v s0 = u.h2[0] + u.h2[1];
    half2v s1 = u.h2[2] + u.h2[3];
    half2v s  = s0 + s1;
    return (float)s[0] + (float)s[1];
}

// ---- kernel 0: cast X fp32 -> fp16 ----
__global__ void cast_x(const float* __restrict__ X, _Float16* __restrict__ Xh) {
    size_t i = ((size_t)blockIdx.x * 256 + threadIdx.x) * 8;
    float4 v0 = *(const float4*)(X + i);
    float4 v1 = *(const float4*)(X + i + 4);
    half8 hh;
    hh[0] = (_Float16)v0.x; hh[1] = (_Float16)v0.y; hh[2] = (_Float16)v0.z; hh[3] = (_Float16)v0.w;
    hh[4] = (_Float16)v1.x; hh[5] = (_Float16)v1.y; hh[6] = (_Float16)v1.z; hh[7] = (_Float16)v1.w;
    *(half8*)(Xh + i) = hh;
}

// ---- kernel 1: transpose-cast weights to fp16 ----
__global__ void prep_weights(const float* __restrict__ Wq, const float* __restrict__ Wk,
                             const float* __restrict__ Wv, _Float16* __restrict__ WbT) {
    int g = blockIdx.z;
    const float* W = (g == 0) ? Wq : (g == 1) ? Wk : Wv;
    __shared__ float tile[32][33];
    int u0 = blockIdx.x * 32, d0 = blockIdx.y * 32;
    int tx = threadIdx.x & 31, ty = threadIdx.x >> 5;
#pragma unroll
    for (int i = 0; i < 32; i += 8)
        tile[ty + i][tx] = W[(size_t)(d0 + ty + i) * 1024 + (u0 + tx)];
    __syncthreads();
#pragma unroll
    for (int i = 0; i < 32; i += 8)
        WbT[(size_t)g * 1024 * 1024 + (size_t)(u0 + ty + i) * 1024 + (d0 + tx)] =
            (_Float16)tile[tx][ty + i];
}

// ---- kernel 2: fused QKV projection ----
__global__ void qkv_gemm(const _Float16* __restrict__ Xh, const _Float16* __restrict__ WbT,
                         _Float16* __restrict__ Qh, _Float16* __restrict__ Kh,
                         _Float16* __restrict__ Vt) {
    __shared__ __align__(16) _Float16 As[BM * BK];
    __shared__ __align__(16) _Float16 Bs[BN * BK];
    int t = threadIdx.x;
    int lane = t & 63, wave = t >> 6;
    int wm = wave >> 1, wn = wave & 1;
    int l31 = lane & 31, h = lane >> 5;
    int m0 = blockIdx.y * BM, n0 = blockIdx.x * BN;
    floatx16 acc[2][2] = {};
    for (int kt = 0; kt < 1024; kt += BK) {
        __syncthreads();
        stage_async(Xh + (size_t)m0 * 1024 + kt, 1024, As, wave, lane);
        stage_async(WbT + (size_t)n0 * 1024 + kt, 1024, Bs, wave, lane);
        __syncthreads();
        mfma_accum(As, Bs, wm, wn, l31, h, acc);
    }
    // C/D 32x32: col=lane&31, row=(reg&3)+8*(reg>>2)+4*(lane>>5)
#pragma unroll
    for (int fi = 0; fi < 2; ++fi)
#pragma unroll
        for (int fj = 0; fj < 2; ++fj)
#pragma unroll
            for (int r = 0; r < 16; ++r) {
                int m = m0 + wm * 64 + fi * 32 + (r & 3) + 8 * (r >> 2) + 4 * h;
                int n = n0 + wn * 64 + fj * 32 + l31;
                int which = n >> 10, u = n & 1023;
                int b = m >> 11, s = m & 2047;
                _Float16 val = (_Float16)acc[fi][fj][r];
                if (which == 0)      Qh[((size_t)b * 2048 + s) * 1024 + u] = val;
                else if (which == 1) Kh[((size_t)b * 2048 + s) * 1024 + u] = val;
                else                 Vt[((size_t)b * 1024 + u) * 2048 + s] = val;
            }
}

// ---- kernel 3: scores, epilogue = exp + store only ----
__global__ void scores_gemm(const _Float16* __restrict__ Qh, const _Float16* __restrict__ Kh,
                            _Float16* __restrict__ P) {
    __shared__ __align__(16) _Float16 As[BM * BK];
    __shared__ __align__(16) _Float16 Bs[BN * BK];
    int t = threadIdx.x;
    int lane = t & 63, wave = t >> 6;
    int wm = wave >> 1, wn = wave & 1;
    int l31 = lane & 31, h = lane >> 5;
    int m0 = blockIdx.y * BM, n0 = blockIdx.x * BN;
    int batch = blockIdx.z;
    const _Float16* A = Qh + (size_t)batch * 2048 * 1024;
    const _Float16* B = Kh + (size_t)batch * 2048 * 1024;
    floatx16 acc[2][2] = {};
    for (int kt = 0; kt < 1024; kt += BK) {
        __syncthreads();
        stage_async(A + (size_t)m0 * 1024 + kt, 1024, As, wave, lane);
        stage_async(B + (size_t)n0 * 1024 + kt, 1024, Bs, wave, lane);
        __syncthreads();
        mfma_accum(As, Bs, wm, wn, l31, h, acc);
    }
    _Float16* Pb = P + (size_t)batch * 2048 * 2048;
#pragma unroll
    for (int fi = 0; fi < 2; ++fi)
#pragma unroll
        for (int fj = 0; fj < 2; ++fj)
#pragma unroll
            for (int r = 0; r < 16; ++r) {
                int m = m0 + wm * 64 + fi * 32 + (r & 3) + 8 * (r >> 2) + 4 * h;
                int n = n0 + wn * 64 + fj * 32 + l31;
                Pb[(size_t)m * 2048 + n] = (_Float16)__expf(acc[fi][fj][r] * 0.03125f);
            }
}

// ---- kernel 4: P @ V with inline rowsum + normalization ----
__global__ void pv_gemm(const _Float16* __restrict__ P, const _Float16* __restrict__ Vt,
                        float* __restrict__ out) {
    __shared__ __align__(16) _Float16 As[BM * BK];
    __shared__ __align__(16) _Float16 Bs[BN * BK];
    int t = threadIdx.x;
    int lane = t & 63, wave = t >> 6;
    int wm = wave >> 1, wn = wave & 1;
    int l31 = lane & 31, h = lane >> 5;
    int m0 = blockIdx.y * BM, n0 = blockIdx.x * BN;
    int batch = blockIdx.z;
    const _Float16* A = P + (size_t)batch * 2048 * 2048;
    const _Float16* B = Vt + (size_t)batch * 1024 * 2048;
    floatx16 acc[2][2] = {};
    float rsum[2] = {0.0f, 0.0f};   // partial rowsum for row wm*64+fi*32+l31 (this lane's k-slice)
    for (int kt = 0; kt < 2048; kt += BK) {
        __syncthreads();
        stage_async(A + (size_t)m0 * 2048 + kt, 2048, As, wave, lane);
        stage_async(B + (size_t)n0 * 2048 + kt, 2048, Bs, wave, lane);
        __syncthreads();
#pragma unroll
        for (int kc = 0; kc < 4; ++kc) {
            int kh = kc * 2 + h;
            half8 a[2], b[2];
#pragma unroll
            for (int fi = 0; fi < 2; ++fi) {
                int row = wm * 64 + fi * 32 + l31;
                a[fi] = *(const half8*)(As + row * 64 + (kh ^ (row & 7)) * 8);
                rsum[fi] += sum8h(a[fi]);
            }
#pragma unroll
            for (int fj = 0; fj < 2; ++fj) {
                int row = wn * 64 + fj * 32 + l31;
                b[fj] = *(const half8*)(Bs + row * 64 + (kh ^ (row & 7)) * 8);
            }
#pragma unroll
            for (int fi = 0; fi < 2; ++fi)
#pragma unroll
                for (int fj = 0; fj < 2; ++fj)
                    acc[fi][fj] = __builtin_amdgcn_mfma_f32_32x32x16_f16(a[fi], b[fj], acc[fi][fj], 0, 0, 0);
        }
    }
    // full rowsum: merge the two k-halves; lane L<32 then holds rowsum of row ..+L
    float rsumf[2];
#pragma unroll
    for (int fi = 0; fi < 2; ++fi)
        rsumf[fi] = rsum[fi] + __shfl_xor(rsum[fi], 32);
    float* ob = out + (size_t)batch * 2048 * 1024;
#pragma unroll
    for (int fi = 0; fi < 2; ++fi)
#pragma unroll
        for (int r = 0; r < 16; ++r) {
            int row32 = (r & 3) + 8 * (r >> 2) + 4 * h;
            float inv = 1.0f / __shfl(rsumf[fi], row32);
            int m = m0 + wm * 64 + fi * 32 + row32;
#pragma unroll
            for (int fj = 0; fj < 2; ++fj) {
                int n = n0 + wn * 64 + fj * 32 + l31;
                ob[(size_t)m * 1024 + n] = acc[fi][fj][r] * inv;
            }
        }
}

extern "C" void kernel_launch(void* const* d_in, const int* in_sizes, int n_in,
                              void* d_out, int out_size, void* d_ws, size_t ws_size,
                              hipStream_t stream) {
    const float* X  = (const float*)d_in[0];
    const float* Wq = (const float*)d_in[1];
    const float* Wk = (const float*)d_in[2];
    const float* Wv = (const float*)d_in[3];
    float* out = (float*)d_out;

    char* ws = (char*)d_ws;
    size_t off = 0;
    _Float16* Xh  = (_Float16*)(ws + off); off += (size_t)8 * 2048 * 1024 * 2;
    _Float16* WbT = (_Float16*)(ws + off); off += (size_t)3 * 1024 * 1024 * 2;
    _Float16* Qh  = (_Float16*)(ws + off); off += (size_t)8 * 2048 * 1024 * 2;
    _Float16* Kh  = (_Float16*)(ws + off); off += (size_t)8 * 2048 * 1024 * 2;
    _Float16* Vt  = (_Float16*)(ws + off); off += (size_t)8 * 1024 * 2048 * 2;
    _Float16* P   = (_Float16*)(ws + off); off += (size_t)8 * 2048 * 2048 * 2;

    cast_x      <<<dim3(8192, 1, 1), 256, 0, stream>>>(X, Xh);
    prep_weights<<<dim3(32, 32, 3), 256, 0, stream>>>(Wq, Wk, Wv, WbT);
    qkv_gemm    <<<dim3(24, 128, 1), 256, 0, stream>>>(Xh, WbT, Qh, Kh, Vt);
    scores_gemm <<<dim3(16, 16, 8),  256, 0, stream>>>(Qh, Kh, P);
    pv_gemm     <<<dim3(8, 16, 8),   256, 0, stream>>>(P, Vt, out);
}

// Round 4
// 398.638 us; speedup vs baseline: 1.2352x; 1.2352x over previous
//
#include <hip/hip_runtime.h>

// SelfAttention: B=8, S=2048, D=1024, U=1024, fp32 in/out.
// R4: revert to R2's 16x16x32 MFMA core (measured 0 LDS bank conflicts; the
// 32x32 frag pattern cost ~4 extra cyc per ds_read_b128 — R3 post-mortem).
// Keep R3's wins: scores epilogue = exp+store only; pv computes rowsum inline
// from its P A-fragments (shfl-merged); qkv epilogue hoists the block-uniform
// Q/K/V branch and packs V's transposed store as 8B half4.
// Staging: global_load_lds(16B) async + XOR swizzle (slot (row,c8) holds
// global colgroup c8^(row&7)) — verified conflict-free in R2.
// Workspace: 33.6(Xh) + 6.3(WbT) + 33.6*3(QKV) + 67.1(P) = 207.7 MB

#define BM 128
#define BN 128
#define BK 64

typedef _Float16 half8  __attribute__((ext_vector_type(8)));
typedef _Float16 half4v __attribute__((ext_vector_type(4)));
typedef _Float16 half2v __attribute__((ext_vector_type(2)));
typedef float    floatx4 __attribute__((ext_vector_type(4)));

// ---- async stage: 128x64 fp16 tile (row-major, ld elems) -> LDS, swizzled ----
__device__ __forceinline__ void stage_async(const _Float16* __restrict__ src, int ld,
                                            _Float16* __restrict__ dst, int wave, int lane) {
#pragma unroll
    for (int i = 0; i < 4; ++i) {
        int chunk = i * 4 + wave;
        int L = chunk * 64 + lane;
        int row = L >> 3, c8 = L & 7;
        int cg = c8 ^ (row & 7);
        __builtin_amdgcn_global_load_lds(
            (const __attribute__((address_space(1))) unsigned int*)(src + (size_t)row * ld + cg * 8),
            (__attribute__((address_space(3))) unsigned int*)(dst + chunk * 512),
            16, 0, 0);
    }
}

// ---- one BK=64 K-step: swizzled ds_read_b128 frags + 16 MFMAs (4x4 16x16x32) ----
__device__ __forceinline__ void mfma_accum(const _Float16* __restrict__ As,
                                           const _Float16* __restrict__ Bs,
                                           int wm, int wn, int l15, int q4,
                                           floatx4 acc[4][4]) {
#pragma unroll
    for (int kk = 0; kk < 2; ++kk) {
        half8 a[4], b[4];
#pragma unroll
        for (int i = 0; i < 4; ++i) {
            int row = wm * 64 + i * 16 + l15;
            int cg = (kk * 4 + q4) ^ (row & 7);
            a[i] = *(const half8*)(As + row * 64 + cg * 8);
        }
#pragma unroll
        for (int j = 0; j < 4; ++j) {
            int row = wn * 64 + j * 16 + l15;
            int cg = (kk * 4 + q4) ^ (row & 7);
            b[j] = *(const half8*)(Bs + row * 64 + cg * 8);
        }
#pragma unroll
        for (int i = 0; i < 4; ++i)
#pragma unroll
            for (int j = 0; j < 4; ++j)
                acc[i][j] = __builtin_amdgcn_mfma_f32_16x16x32_f16(a[i], b[j], acc[i][j], 0, 0, 0);
    }
}

// pk-add sum of 8 halves -> float
__device__ __forceinline__ float sum8h(half8 a) {
    union { half8 v; half2v h2[4]; } u; u.v = a;
    half2v s0 = u.h2[0] + u.h2[1];
    half2v s1 = u.h2[2] + u.h2[3];
    half2v s  = s0 + s1;
    return (float)s[0] + (float)s[1];
}

// ---- kernel 0: cast X fp32 -> fp16 ----
__global__ void cast_x(const float* __restrict__ X, _Float16* __restrict__ Xh) {
    size_t i = ((size_t)blockIdx.x * 256 + threadIdx.x) * 8;
    float4 v0 = *(const float4*)(X + i);
    float4 v1 = *(const float4*)(X + i + 4);
    half8 hh;
    hh[0] = (_Float16)v0.x; hh[1] = (_Float16)v0.y; hh[2] = (_Float16)v0.z; hh[3] = (_Float16)v0.w;
    hh[4] = (_Float16)v1.x; hh[5] = (_Float16)v1.y; hh[6] = (_Float16)v1.z; hh[7] = (_Float16)v1.w;
    *(half8*)(Xh + i) = hh;
}

// ---- kernel 1: transpose-cast weights to fp16 ----
__global__ void prep_weights(const float* __restrict__ Wq, const float* __restrict__ Wk,
                             const float* __restrict__ Wv, _Float16* __restrict__ WbT) {
    int g = blockIdx.z;
    const float* W = (g == 0) ? Wq : (g == 1) ? Wk : Wv;
    __shared__ float tile[32][33];
    int u0 = blockIdx.x * 32, d0 = blockIdx.y * 32;
    int tx = threadIdx.x & 31, ty = threadIdx.x >> 5;
#pragma unroll
    for (int i = 0; i < 32; i += 8)
        tile[ty + i][tx] = W[(size_t)(d0 + ty + i) * 1024 + (u0 + tx)];
    __syncthreads();
#pragma unroll
    for (int i = 0; i < 32; i += 8)
        WbT[(size_t)g * 1024 * 1024 + (size_t)(u0 + ty + i) * 1024 + (d0 + tx)] =
            (_Float16)tile[tx][ty + i];
}

// ---- kernel 2: fused QKV projection ----
// grid (24,128): blockIdx.x>>3 selects Q/K/V (block-uniform), &7 is the u-tile.
__global__ void qkv_gemm(const _Float16* __restrict__ Xh, const _Float16* __restrict__ WbT,
                         _Float16* __restrict__ Qh, _Float16* __restrict__ Kh,
                         _Float16* __restrict__ Vt) {
    __shared__ __align__(16) _Float16 As[BM * BK];
    __shared__ __align__(16) _Float16 Bs[BN * BK];
    int t = threadIdx.x;
    int lane = t & 63, wave = t >> 6;
    int wm = wave >> 1, wn = wave & 1;
    int l15 = lane & 15, q4 = lane >> 4;
    int m0 = blockIdx.y * BM, n0 = blockIdx.x * BN;
    floatx4 acc[4][4] = {};
    for (int kt = 0; kt < 1024; kt += BK) {
        __syncthreads();
        stage_async(Xh + (size_t)m0 * 1024 + kt, 1024, As, wave, lane);
        stage_async(WbT + (size_t)n0 * 1024 + kt, 1024, Bs, wave, lane);
        __syncthreads();
        mfma_accum(As, Bs, wm, wn, l15, q4, acc);
    }
    // block-uniform routing: which matrix, which batch
    int which = blockIdx.x >> 3;            // 0=Q 1=K 2=V
    int u0 = (blockIdx.x & 7) * BN;         // column offset within 1024
    int b = m0 >> 11;                       // batch (128-row tiles never straddle)
    int sbase = (m0 & 2047) + wm * 64;      // sequence offset of this wave's rows
    if (which < 2) {
        _Float16* dst = which ? Kh : Qh;
        _Float16* db = dst + (size_t)b * 2048 * 1024;
#pragma unroll
        for (int i = 0; i < 4; ++i)
#pragma unroll
            for (int j = 0; j < 4; ++j)
#pragma unroll
                for (int r = 0; r < 4; ++r) {
                    int s = sbase + i * 16 + q4 * 4 + r;
                    int u = u0 + wn * 64 + j * 16 + l15;
                    db[(size_t)s * 1024 + u] = (_Float16)acc[i][j][r];
                }
    } else {
        _Float16* vb = Vt + (size_t)b * 1024 * 2048;
#pragma unroll
        for (int i = 0; i < 4; ++i)
#pragma unroll
            for (int j = 0; j < 4; ++j) {
                int s = sbase + i * 16 + q4 * 4;          // 4 consecutive s (r=0..3)
                int u = u0 + wn * 64 + j * 16 + l15;
                half4v pk;
#pragma unroll
                for (int r = 0; r < 4; ++r) pk[r] = (_Float16)acc[i][j][r];
                *(half4v*)(vb + (size_t)u * 2048 + s) = pk;  // 8B aligned (s%4==0)
            }
    }
}

// ---- kernel 3: scores, epilogue = exp + store only ----
__global__ void scores_gemm(const _Float16* __restrict__ Qh, const _Float16* __restrict__ Kh,
                            _Float16* __restrict__ P) {
    __shared__ __align__(16) _Float16 As[BM * BK];
    __shared__ __align__(16) _Float16 Bs[BN * BK];
    int t = threadIdx.x;
    int lane = t & 63, wave = t >> 6;
    int wm = wave >> 1, wn = wave & 1;
    int l15 = lane & 15, q4 = lane >> 4;
    int m0 = blockIdx.y * BM, n0 = blockIdx.x * BN;
    int batch = blockIdx.z;
    const _Float16* A = Qh + (size_t)batch * 2048 * 1024;
    const _Float16* B = Kh + (size_t)batch * 2048 * 1024;
    floatx4 acc[4][4] = {};
    for (int kt = 0; kt < 1024; kt += BK) {
        __syncthreads();
        stage_async(A + (size_t)m0 * 1024 + kt, 1024, As, wave, lane);
        stage_async(B + (size_t)n0 * 1024 + kt, 1024, Bs, wave, lane);
        __syncthreads();
        mfma_accum(As, Bs, wm, wn, l15, q4, acc);
    }
    _Float16* Pb = P + (size_t)batch * 2048 * 2048;
#pragma unroll
    for (int i = 0; i < 4; ++i)
#pragma unroll
        for (int j = 0; j < 4; ++j)
#pragma unroll
            for (int r = 0; r < 4; ++r) {
                int m = m0 + wm * 64 + i * 16 + q4 * 4 + r;
                int n = n0 + wn * 64 + j * 16 + l15;
                Pb[(size_t)m * 2048 + n] = (_Float16)__expf(acc[i][j][r] * 0.03125f);
            }
}

// ---- kernel 4: P @ V with inline rowsum + normalization ----
__global__ void pv_gemm(const _Float16* __restrict__ P, const _Float16* __restrict__ Vt,
                        float* __restrict__ out) {
    __shared__ __align__(16) _Float16 As[BM * BK];
    __shared__ __align__(16) _Float16 Bs[BN * BK];
    int t = threadIdx.x;
    int lane = t & 63, wave = t >> 6;
    int wm = wave >> 1, wn = wave & 1;
    int l15 = lane & 15, q4 = lane >> 4;
    int m0 = blockIdx.y * BM, n0 = blockIdx.x * BN;
    int batch = blockIdx.z;
    const _Float16* A = P + (size_t)batch * 2048 * 2048;
    const _Float16* B = Vt + (size_t)batch * 1024 * 2048;
    floatx4 acc[4][4] = {};
    float rsum[4] = {0.f, 0.f, 0.f, 0.f};  // partial rowsum of row i*16+l15, this lane's k-slices
    for (int kt = 0; kt < 2048; kt += BK) {
        __syncthreads();
        stage_async(A + (size_t)m0 * 2048 + kt, 2048, As, wave, lane);
        stage_async(B + (size_t)n0 * 2048 + kt, 2048, Bs, wave, lane);
        __syncthreads();
#pragma unroll
        for (int kk = 0; kk < 2; ++kk) {
            half8 a[4], b[4];
#pragma unroll
            for (int i = 0; i < 4; ++i) {
                int row = wm * 64 + i * 16 + l15;
                int cg = (kk * 4 + q4) ^ (row & 7);
                a[i] = *(const half8*)(As + row * 64 + cg * 8);
                rsum[i] += sum8h(a[i]);
            }
#pragma unroll
            for (int j = 0; j < 4; ++j) {
                int row = wn * 64 + j * 16 + l15;
                int cg = (kk * 4 + q4) ^ (row & 7);
                b[j] = *(const half8*)(Bs + row * 64 + cg * 8);
            }
#pragma unroll
            for (int i = 0; i < 4; ++i)
#pragma unroll
                for (int j = 0; j < 4; ++j)
                    acc[i][j] = __builtin_amdgcn_mfma_f32_16x16x32_f16(a[i], b[j], acc[i][j], 0, 0, 0);
        }
    }
    // merge the 4 q4 k-slices: lanes sharing l15 hold partials of the same row
    float rsumf[4];
#pragma unroll
    for (int i = 0; i < 4; ++i) {
        float v = rsum[i] + __shfl_xor(rsum[i], 16);
        rsumf[i] = v + __shfl_xor(v, 32);   // full rowsum of row i*16+l15, all lanes
    }
    float* ob = out + (size_t)batch * 2048 * 1024;
#pragma unroll
    for (int i = 0; i < 4; ++i)
#pragma unroll
        for (int r = 0; r < 4; ++r) {
            int rloc = q4 * 4 + r;                       // C/D row within 16x16
            float inv = 1.0f / __shfl(rsumf[i], rloc);   // lane rloc holds row rloc's sum
            int m = m0 + wm * 64 + i * 16 + rloc;
#pragma unroll
            for (int j = 0; j < 4; ++j) {
                int n = n0 + wn * 64 + j * 16 + l15;
                ob[(size_t)m * 1024 + n] = acc[i][j][r] * inv;
            }
        }
}

extern "C" void kernel_launch(void* const* d_in, const int* in_sizes, int n_in,
                              void* d_out, int out_size, void* d_ws, size_t ws_size,
                              hipStream_t stream) {
    const float* X  = (const float*)d_in[0];
    const float* Wq = (const float*)d_in[1];
    const float* Wk = (const float*)d_in[2];
    const float* Wv = (const float*)d_in[3];
    float* out = (float*)d_out;

    char* ws = (char*)d_ws;
    size_t off = 0;
    _Float16* Xh  = (_Float16*)(ws + off); off += (size_t)8 * 2048 * 1024 * 2;
    _Float16* WbT = (_Float16*)(ws + off); off += (size_t)3 * 1024 * 1024 * 2;
    _Float16* Qh  = (_Float16*)(ws + off); off += (size_t)8 * 2048 * 1024 * 2;
    _Float16* Kh  = (_Float16*)(ws + off); off += (size_t)8 * 2048 * 1024 * 2;
    _Float16* Vt  = (_Float16*)(ws + off); off += (size_t)8 * 1024 * 2048 * 2;
    _Float16* P   = (_Float16*)(ws + off); off += (size_t)8 * 2048 * 2048 * 2;

    cast_x      <<<dim3(8192, 1, 1), 256, 0, stream>>>(X, Xh);
    prep_weights<<<dim3(32, 32, 3), 256, 0, stream>>>(Wq, Wk, Wv, WbT);
    qkv_gemm    <<<dim3(24, 128, 1), 256, 0, stream>>>(Xh, WbT, Qh, Kh, Vt);
    scores_gemm <<<dim3(16, 16, 8),  256, 0, stream>>>(Qh, Kh, P);
    pv_gemm     <<<dim3(8, 16, 8),   256, 0, stream>>>(P, Vt, out);
}